// Round 19
// baseline (102.611 us; speedup 1.0000x reference)
//
#include <hip/hip_runtime.h>
#include <hip/hip_cooperative_groups.h>
#include <stdint.h>

namespace cg = cooperative_groups;

// ---------------- problem constants ----------------
#define B_ROWS 16384
#define NF 26
#define NV 100000
#define ND 13
#define NH 400
#define XPAD 448     // GEMM1 K padded (14 tiles of 32)
#define ZPAD 416     // GEMM2 K padded (13 tiles of 32)
#define EPS 1e-5f

typedef __attribute__((ext_vector_type(8))) short short8;
typedef __attribute__((ext_vector_type(4))) float f32x4;
typedef __attribute__((ext_vector_type(4))) unsigned int uint4v;

__device__ inline float bf2f(unsigned short u) {
    union { unsigned int i; float f; } v; v.i = (unsigned int)u << 16; return v.f;
}
__device__ inline unsigned short f2bf(float f) {
    union { float f; unsigned int i; } v; v.f = f;
    return (unsigned short)((v.i + 0x7fff + ((v.i >> 16) & 1)) >> 16);
}

// direct global->LDS DMA; one call = 64 lanes x 16B = 1024B at dest base
typedef __attribute__((address_space(1))) const unsigned int g_u32;
typedef __attribute__((address_space(3))) unsigned int l_u32;
__device__ __forceinline__ void gload_lds16(const void* g, void* l) {
    __builtin_amdgcn_global_load_lds((g_u32*)g, (l_u32*)l, 16, 0, 0);
}

// ---------------- ws layout (bytes) ----------------
#define X_OFF    0
#define Z1_OFF   14680064
#define W1S_OFF  28311552
#define W2S_OFF  28712960
#define BASE_OFF 29085696
#define ST_OFF   29151232

// =====================================================================
// gather (blocks 0..1023) + W-staging/stat-zero (blocks 1024..1212)
// (R16 champion, unchanged)
// =====================================================================
__global__ __launch_bounds__(256) void gather_prep(
    const int* __restrict__ Xcat, const float* __restrict__ Xdense,
    const float* __restrict__ fm1, const float* __restrict__ emb,
    const float* __restrict__ Wd, const float* __restrict__ bd,
    const float* __restrict__ W1, const float* __restrict__ W2,
    unsigned short* __restrict__ X, float* __restrict__ base,
    unsigned short* __restrict__ W1s, unsigned short* __restrict__ W2s,
    float* __restrict__ st)
{
    int tid = threadIdx.x;
    if (blockIdx.x >= 1024) {
        int c = (blockIdx.x - 1024) * 256 + tid;     // 0..48383
        if (c < 256) {
            for (int i = tid; i < 6656; i += 256) st[i] = 0.f;  // 4 replicas
        }
        const float* W; unsigned short* dst; int K; int cc;
        if (c < 25088) { W = W1; dst = W1s; K = 429; cc = c; }
        else           { W = W2; dst = W2s; K = 400; cc = c - 25088; }
        int n  = cc % 448;
        int q  = (cc / 448) & 3;
        int kt = cc / 1792;
        unsigned short o[8];
        #pragma unroll
        for (int j = 0; j < 8; ++j) {
            int k = kt * 32 + q * 8 + j;
            float v = (n < NH && k < K) ? W[(size_t)k * NH + n] : 0.f;
            o[j] = f2bf(v);
        }
        *(uint4v*)(dst + (size_t)cc * 8) = *(uint4v*)o;
        return;
    }
    int r = blockIdx.x * 16 + (tid >> 4);
    int k = tid & 15;
    const int* idxp = Xcat + (size_t)r * NF;
    unsigned short* xrow = X + (size_t)r * XPAD;

    float s = 0.f, ss = 0.f;
    #pragma unroll
    for (int f = 0; f < NF; ++f) {
        int idx = idxp[f];
        float v = emb[((size_t)f * NV + idx) * 16 + k];
        s += v; ss += v * v;
        xrow[f * 16 + k] = f2bf(v);
    }
    float fmsum = fm1[(size_t)k * NV + idxp[k]];
    if (k < NF - 16) fmsum += fm1[(size_t)(k + 16) * NV + idxp[k + 16]];
    float dsum = 0.f;
    if (k < ND) {
        float xd = Xdense[(size_t)r * ND + k];
        dsum = xd * Wd[k];
        xrow[NF * 16 + k] = f2bf(xd);
    }
    xrow[429 + k] = 0;
    if (k < 3) xrow[445 + k] = 0;

    float ix = s * s - ss;
    float rf = fmsum, rd = dsum;
    #pragma unroll
    for (int off = 8; off; off >>= 1) {
        ix += __shfl_xor(ix, off, 16);
        rf += __shfl_xor(rf, off, 16);
        rd += __shfl_xor(rd, off, 16);
    }
    if (k == 0) base[r] = 0.5f * ix + rf + rd + bd[0];
}

// =====================================================================
// gemm_v5 (R16 champion, verbatim) — used for GEMM1 only.
// =====================================================================
template<int NT, int LDA, bool APPLY_BN>
__global__ __launch_bounds__(512, 2) void gemm_v5(
    const unsigned short* __restrict__ A,
    const unsigned short* __restrict__ Wst,
    const float* __restrict__ bias,
    const float* __restrict__ st_all,
    const float* __restrict__ g, const float* __restrict__ be,
    unsigned short* __restrict__ Z, int ldz, int padZ,
    float* __restrict__ st_out, int sumOff, int sqOff)
{
    __shared__ __align__(16) unsigned short slices[51200];  // 2 bufs x 25600
    __shared__ float alpha_s[416], beta_s[416];

    const int tid = threadIdx.x, bid = blockIdx.x;
    const int lane = tid & 63, wv = tid >> 6;
    const int rg = wv >> 2, w4 = wv & 3;
    const int l15 = lane & 15, qh = lane >> 4;
    const int cb = (w4 == 0) ? 0 : (112 + (w4 - 1) * 96);
    const int NFW = (w4 == 0) ? 7 : 6;
    const int soff = rg * 12800 + ((w4 == 0) ? 0 : (3584 + (w4 - 1) * 3072));
    const int arowA = bid * 64 + rg * 32 + l15;
    const int arowB = arowA + 16;

    if constexpr (APPLY_BN) {
        if (tid < 416) {
            int c = tid;
            float a = 0.f, b = 0.f;
            if (c < NH) {
                float gs = 0.f, gq = 0.f;
                #pragma unroll
                for (int cp = 0; cp < 4; ++cp) {
                    gs += st_all[cp * 1664 + c];
                    gq += st_all[cp * 1664 + 416 + c];
                }
                float mean = gs * (1.f / 16384.f);
                float var  = gq * (1.f / 16384.f) - mean * mean;
                a = g[c] * rsqrtf(var + EPS);
                b = be[c] - mean * a;
            }
            alpha_s[c] = a; beta_s[c] = b;
        }
        __syncthreads();
    }

    f32x4 acc0[7], acc1[7];
    #pragma unroll
    for (int i = 0; i < 7; ++i) { acc0[i] = f32x4{0,0,0,0}; acc1[i] = f32x4{0,0,0,0}; }

    auto stageW = [&](int kt, int buf) {
        unsigned short* sl = slices + buf * 25600 + soff;
        #pragma unroll
        for (int i = 0; i < 7; ++i) if (i < NFW) {
            int ci = (kt * 4 + qh) * 448 + cb + i * 16 + l15;
            gload_lds16(Wst + (size_t)ci * 8, sl + i * 512);
        }
    };
    auto ldA = [&](int kt, short8& a, short8& b) {
        a = *(const short8*)(A + (size_t)arowA * LDA + kt * 32 + qh * 8);
        b = *(const short8*)(A + (size_t)arowB * LDA + kt * 32 + qh * 8);
    };
    auto waitN = [&]() {
        if (w4 == 0) asm volatile("s_waitcnt vmcnt(9)" ::: "memory");
        else         asm volatile("s_waitcnt vmcnt(8)" ::: "memory");
        __builtin_amdgcn_sched_barrier(0);
    };
    auto wait0 = [&]() {
        asm volatile("s_waitcnt vmcnt(0)" ::: "memory");
        __builtin_amdgcn_sched_barrier(0);
    };
    auto waitlg = [&]() {
        asm volatile("s_waitcnt lgkmcnt(0)" ::: "memory");
        __builtin_amdgcn_sched_barrier(0);
    };

    auto phase = [&](int kt, int buf, bool last, bool issue,
                     short8& afA, short8& afB) {
        if (last) wait0(); else waitN();
        const unsigned short* sl = slices + buf * 25600 + soff;
        short8 bf[7];
        #pragma unroll
        for (int i = 0; i < 7; ++i) if (i < NFW)
            bf[i] = *(const short8*)(sl + i * 512 + lane * 8);
        short8 aA = afA, aB = afB;
        waitlg();
        if (issue) { stageW(kt + 2, buf); ldA(kt + 2, afA, afB); }
        if constexpr (APPLY_BN) {
            const int k0 = kt * 32 + qh * 8;
            #pragma unroll
            for (int j = 0; j < 8; ++j) {
                float al = alpha_s[k0 + j], bt = beta_s[k0 + j];
                aA[j] = (short)f2bf(fmaxf(0.f, al * bf2f((unsigned short)aA[j]) + bt));
                aB[j] = (short)f2bf(fmaxf(0.f, al * bf2f((unsigned short)aB[j]) + bt));
            }
        }
        #pragma unroll
        for (int i = 0; i < 7; ++i) if (i < NFW) {
            acc0[i] = __builtin_amdgcn_mfma_f32_16x16x32_bf16(aA, bf[i], acc0[i], 0, 0, 0);
            acc1[i] = __builtin_amdgcn_mfma_f32_16x16x32_bf16(aB, bf[i], acc1[i], 0, 0, 0);
        }
    };

    short8 afA0, afB0, afA1, afB1;
    stageW(0, 0); ldA(0, afA0, afB0);
    stageW(1, 1); ldA(1, afA1, afB1);

    int kt2 = 0;
    for (; kt2 + 3 < NT; kt2 += 2) {
        phase(kt2,     0, false, true, afA0, afB0);
        phase(kt2 + 1, 1, false, true, afA1, afB1);
    }
    if constexpr (NT % 2 == 0) {
        phase(NT - 2, 0, false, false, afA0, afB0);
        phase(NT - 1, 1, true,  false, afA1, afB1);
    } else {
        phase(NT - 3, 0, false, true,  afA0, afB0);
        phase(NT - 2, 1, false, false, afA1, afB1);
        phase(NT - 1, 0, true,  false, afA0, afB0);
    }

    float* stc = st_out + (bid & 3) * 1664;
    #pragma unroll
    for (int i = 0; i < 7; ++i) if (i < NFW) {
        int col = cb + i * 16 + l15;
        float bv = bias[col];
        float ps = 0.f, pq = 0.f;
        #pragma unroll
        for (int q = 0; q < 4; ++q) {
            float v0 = acc0[i][q] + bv;
            float v1 = acc1[i][q] + bv;
            Z[(size_t)(bid * 64 + rg * 32 + qh * 4 + q) * ldz + col] = f2bf(v0);
            Z[(size_t)(bid * 64 + rg * 32 + 16 + qh * 4 + q) * ldz + col] = f2bf(v1);
            ps += v0 + v1; pq += v0 * v0 + v1 * v1;
        }
        ps += __shfl_xor(ps, 16, 64); ps += __shfl_xor(ps, 32, 64);
        pq += __shfl_xor(pq, 16, 64); pq += __shfl_xor(pq, 32, 64);
        if (qh == 0) {
            atomicAdd(&stc[sumOff + col], ps);
            atomicAdd(&stc[sqOff + col], pq);
        }
    }
    if (padZ && w4 == 3) {
        #pragma unroll
        for (int rr = 0; rr < 8; ++rr)
            Z[(size_t)(bid * 64 + rg * 32 + rr * 4 + qh) * ldz + 400 + l15] = 0;
    }
}

// =====================================================================
// gemm2_final: cooperative, grid 256 x 512. R16's K-loop verbatim
// (NT=13, BN1 on A), but NO Z2 store: stats2 atomics -> grid.sync ->
// BN2 finalize -> final dot from fp32 accumulators -> out.
// =====================================================================
__global__ __launch_bounds__(512, 2) void gemm2_final(
    const unsigned short* __restrict__ A,       // Z1
    const unsigned short* __restrict__ Wst,     // W2s
    const float* __restrict__ b2,
    float* __restrict__ st,                     // replicas (rw)
    const float* __restrict__ g1, const float* __restrict__ be1,
    const float* __restrict__ g2, const float* __restrict__ be2,
    const float* __restrict__ W3, const float* __restrict__ b3,
    const float* __restrict__ base, float* __restrict__ out)
{
    cg::grid_group grid = cg::this_grid();
    __shared__ __align__(16) unsigned short slices[51200];
    __shared__ float alpha_s[416], beta_s[416];
    __shared__ float rowacc[64 * 4];

    const int tid = threadIdx.x, bid = blockIdx.x;
    const int lane = tid & 63, wv = tid >> 6;
    const int rg = wv >> 2, w4 = wv & 3;
    const int l15 = lane & 15, qh = lane >> 4;
    const int cb = (w4 == 0) ? 0 : (112 + (w4 - 1) * 96);
    const int NFW = (w4 == 0) ? 7 : 6;
    const int soff = rg * 12800 + ((w4 == 0) ? 0 : (3584 + (w4 - 1) * 3072));
    const int arowA = bid * 64 + rg * 32 + l15;
    const int arowB = arowA + 16;

    // BN1 finalize into LDS
    if (tid < 416) {
        int c = tid;
        float a = 0.f, b = 0.f;
        if (c < NH) {
            float gs = 0.f, gq = 0.f;
            #pragma unroll
            for (int cp = 0; cp < 4; ++cp) {
                gs += st[cp * 1664 + c];
                gq += st[cp * 1664 + 416 + c];
            }
            float mean = gs * (1.f / 16384.f);
            float var  = gq * (1.f / 16384.f) - mean * mean;
            a = g1[c] * rsqrtf(var + EPS);
            b = be1[c] - mean * a;
        }
        alpha_s[c] = a; beta_s[c] = b;
    }
    __syncthreads();

    f32x4 acc0[7], acc1[7];
    #pragma unroll
    for (int i = 0; i < 7; ++i) { acc0[i] = f32x4{0,0,0,0}; acc1[i] = f32x4{0,0,0,0}; }

    auto stageW = [&](int kt, int buf) {
        unsigned short* sl = slices + buf * 25600 + soff;
        #pragma unroll
        for (int i = 0; i < 7; ++i) if (i < NFW) {
            int ci = (kt * 4 + qh) * 448 + cb + i * 16 + l15;
            gload_lds16(Wst + (size_t)ci * 8, sl + i * 512);
        }
    };
    auto ldA = [&](int kt, short8& a, short8& b) {
        a = *(const short8*)(A + (size_t)arowA * ZPAD + kt * 32 + qh * 8);
        b = *(const short8*)(A + (size_t)arowB * ZPAD + kt * 32 + qh * 8);
    };
    auto waitN = [&]() {
        if (w4 == 0) asm volatile("s_waitcnt vmcnt(9)" ::: "memory");
        else         asm volatile("s_waitcnt vmcnt(8)" ::: "memory");
        __builtin_amdgcn_sched_barrier(0);
    };
    auto wait0 = [&]() {
        asm volatile("s_waitcnt vmcnt(0)" ::: "memory");
        __builtin_amdgcn_sched_barrier(0);
    };
    auto waitlg = [&]() {
        asm volatile("s_waitcnt lgkmcnt(0)" ::: "memory");
        __builtin_amdgcn_sched_barrier(0);
    };

    auto phase = [&](int kt, int buf, bool last, bool issue,
                     short8& afA, short8& afB) {
        if (last) wait0(); else waitN();
        const unsigned short* sl = slices + buf * 25600 + soff;
        short8 bf[7];
        #pragma unroll
        for (int i = 0; i < 7; ++i) if (i < NFW)
            bf[i] = *(const short8*)(sl + i * 512 + lane * 8);
        short8 aA = afA, aB = afB;
        waitlg();
        if (issue) { stageW(kt + 2, buf); ldA(kt + 2, afA, afB); }
        {
            const int k0 = kt * 32 + qh * 8;
            #pragma unroll
            for (int j = 0; j < 8; ++j) {
                float al = alpha_s[k0 + j], bt = beta_s[k0 + j];
                aA[j] = (short)f2bf(fmaxf(0.f, al * bf2f((unsigned short)aA[j]) + bt));
                aB[j] = (short)f2bf(fmaxf(0.f, al * bf2f((unsigned short)aB[j]) + bt));
            }
        }
        #pragma unroll
        for (int i = 0; i < 7; ++i) if (i < NFW) {
            acc0[i] = __builtin_amdgcn_mfma_f32_16x16x32_bf16(aA, bf[i], acc0[i], 0, 0, 0);
            acc1[i] = __builtin_amdgcn_mfma_f32_16x16x32_bf16(aB, bf[i], acc1[i], 0, 0, 0);
        }
    };

    short8 afA0, afB0, afA1, afB1;
    stageW(0, 0); ldA(0, afA0, afB0);
    stageW(1, 1); ldA(1, afA1, afB1);

    int kt2 = 0;
    for (; kt2 + 3 < 13; kt2 += 2) {
        phase(kt2,     0, false, true, afA0, afB0);
        phase(kt2 + 1, 1, false, true, afA1, afB1);
    }
    phase(10, 0, false, true,  afA0, afB0);   // issues tile 12 -> buf0
    phase(11, 1, false, false, afA1, afB1);
    phase(12, 0, true,  false, afA0, afB0);

    // ---- stats2 only (no Z2 store) ----
    float* stc = st + (bid & 3) * 1664;
    #pragma unroll
    for (int i = 0; i < 7; ++i) if (i < NFW) {
        int col = cb + i * 16 + l15;
        float bv = b2[col];
        float ps = 0.f, pq = 0.f;
        #pragma unroll
        for (int q = 0; q < 4; ++q) {
            float v0 = acc0[i][q] + bv;
            float v1 = acc1[i][q] + bv;
            ps += v0 + v1; pq += v0 * v0 + v1 * v1;
        }
        ps += __shfl_xor(ps, 16, 64); ps += __shfl_xor(ps, 32, 64);
        pq += __shfl_xor(pq, 16, 64); pq += __shfl_xor(pq, 32, 64);
        if (qh == 0) {
            atomicAdd(&stc[832 + col], ps);
            atomicAdd(&stc[1248 + col], pq);
        }
    }
    grid.sync();   // stats2 complete grid-wide

    // ---- BN2 finalize into LDS (overwrites BN1 alpha/beta) ----
    if (tid < NH) {
        int c = tid;
        float gs = 0.f, gq = 0.f;
        #pragma unroll
        for (int cp = 0; cp < 4; ++cp) {
            gs += st[cp * 1664 + 832 + c];
            gq += st[cp * 1664 + 1248 + c];
        }
        float mean = gs * (1.f / 16384.f);
        float var  = gq * (1.f / 16384.f) - mean * mean;
        float a = g2[c] * rsqrtf(var + EPS);
        alpha_s[c] = a;
        beta_s[c]  = be2[c] - mean * a;
    }
    __syncthreads();

    // ---- final dot from accumulators ----
    {
        float bv[7], w3v[7], av[7], btv[7];
        #pragma unroll
        for (int i = 0; i < 7; ++i) if (i < NFW) {
            int col = cb + i * 16 + l15;
            bv[i] = b2[col]; w3v[i] = W3[col];
            av[i] = alpha_s[col]; btv[i] = beta_s[col];
        }
        #pragma unroll
        for (int q = 0; q < 4; ++q) {
            float p0 = 0.f, p1 = 0.f;
            #pragma unroll
            for (int i = 0; i < 7; ++i) if (i < NFW) {
                float v0 = acc0[i][q] + bv[i];
                float v1 = acc1[i][q] + bv[i];
                p0 += fmaxf(0.f, av[i] * v0 + btv[i]) * w3v[i];
                p1 += fmaxf(0.f, av[i] * v1 + btv[i]) * w3v[i];
            }
            p0 += __shfl_xor(p0, 1, 64); p0 += __shfl_xor(p0, 2, 64);
            p0 += __shfl_xor(p0, 4, 64); p0 += __shfl_xor(p0, 8, 64);
            p1 += __shfl_xor(p1, 1, 64); p1 += __shfl_xor(p1, 2, 64);
            p1 += __shfl_xor(p1, 4, 64); p1 += __shfl_xor(p1, 8, 64);
            if (l15 == 0) {
                rowacc[(rg * 32 + qh * 4 + q) * 4 + w4] = p0;
                rowacc[(rg * 32 + 16 + qh * 4 + q) * 4 + w4] = p1;
            }
        }
    }
    __syncthreads();
    if (tid < 64) {
        int r = bid * 64 + tid;
        float s = rowacc[tid * 4] + rowacc[tid * 4 + 1]
                + rowacc[tid * 4 + 2] + rowacc[tid * 4 + 3];
        out[r] = base[r] + s + b3[0];
    }
}

// =====================================================================
extern "C" void kernel_launch(void* const* d_in, const int* in_sizes, int n_in,
                              void* d_out, int out_size, void* d_ws, size_t ws_size,
                              hipStream_t stream)
{
    const int*   Xcat = (const int*)d_in[0];
    const float* Xd   = (const float*)d_in[1];
    const float* fm1  = (const float*)d_in[2];
    const float* emb  = (const float*)d_in[3];
    const float* Wd   = (const float*)d_in[4];
    const float* bd   = (const float*)d_in[5];
    const float* W1   = (const float*)d_in[6];
    const float* b1   = (const float*)d_in[7];
    const float* g1   = (const float*)d_in[8];
    const float* be1  = (const float*)d_in[9];
    const float* W2   = (const float*)d_in[10];
    const float* b2   = (const float*)d_in[11];
    const float* g2   = (const float*)d_in[12];
    const float* be2  = (const float*)d_in[13];
    const float* W3   = (const float*)d_in[14];
    const float* b3   = (const float*)d_in[15];

    char* ws = (char*)d_ws;
    unsigned short* X   = (unsigned short*)(ws + X_OFF);
    unsigned short* Z1  = (unsigned short*)(ws + Z1_OFF);
    unsigned short* W1s = (unsigned short*)(ws + W1S_OFF);
    unsigned short* W2s = (unsigned short*)(ws + W2S_OFF);
    float* base = (float*)(ws + BASE_OFF);
    float* st   = (float*)(ws + ST_OFF);
    float* out  = (float*)d_out;

    // 1: gather + W staging + 4-replica stat zero
    gather_prep<<<1213, 256, 0, stream>>>(Xcat, Xd, fm1, emb, Wd, bd, W1, W2,
                                          X, base, W1s, W2s, st);

    // 2: Z1 = X @ W1 + b1, stats1 (R16 champion GEMM)
    gemm_v5<14, XPAD, false><<<256, 512, 0, stream>>>(
        X, W1s, b1, nullptr, nullptr, nullptr, Z1, ZPAD, 1, st, 0, 416);

    // 3: cooperative: K2 (no Z2 store) -> stats2 -> grid.sync -> BN2 ->
    //    final dot from accumulators -> out
    void* args[] = {
        (void*)&Z1, (void*)&W2s, (void*)&b2, (void*)&st,
        (void*)&g1, (void*)&be1, (void*)&g2, (void*)&be2,
        (void*)&W3, (void*)&b3, (void*)&base, (void*)&out
    };
    hipLaunchCooperativeKernel((const void*)gemm2_final, dim3(256), dim3(512),
                               args, 0, stream);
}

// Round 20
// 72.787 us; speedup vs baseline: 1.4097x; 1.4097x over previous
//
#include <hip/hip_runtime.h>
#include <stdint.h>

// ---------------- problem constants ----------------
#define B_ROWS 16384
#define NF 26
#define NV 100000
#define ND 13
#define NH 400
#define XPAD 448     // GEMM1 K padded (14 tiles of 32)
#define ZPAD 416     // GEMM2 K padded (13 tiles of 32)
#define EPS 1e-5f

typedef __attribute__((ext_vector_type(8))) short short8;
typedef __attribute__((ext_vector_type(4))) float f32x4;
typedef __attribute__((ext_vector_type(4))) unsigned int uint4v;

__device__ inline float bf2f(unsigned short u) {
    union { unsigned int i; float f; } v; v.i = (unsigned int)u << 16; return v.f;
}
__device__ inline unsigned short f2bf(float f) {
    union { float f; unsigned int i; } v; v.f = f;
    return (unsigned short)((v.i + 0x7fff + ((v.i >> 16) & 1)) >> 16);
}

// direct global->LDS DMA; one call = 64 lanes x 16B = 1024B at dest base
typedef __attribute__((address_space(1))) const unsigned int g_u32;
typedef __attribute__((address_space(3))) unsigned int l_u32;
__device__ __forceinline__ void gload_lds16(const void* g, void* l) {
    __builtin_amdgcn_global_load_lds((g_u32*)g, (l_u32*)l, 16, 0, 0);
}

// ---------------- ws layout (bytes) ----------------
#define X_OFF    0
#define Z1_OFF   14680064
#define W1S_OFF  28311552
#define W2S_OFF  28712960
#define BASE_OFF 29085696
#define ST_OFF   29151232

// =====================================================================
// gather (blocks 0..1023) + W-staging/stat-zero (blocks 1024..1212)
// 16 rows x 16 lanes; 26 independent emb loads in flight per thread.
// =====================================================================
__global__ __launch_bounds__(256) void gather_prep(
    const int* __restrict__ Xcat, const float* __restrict__ Xdense,
    const float* __restrict__ fm1, const float* __restrict__ emb,
    const float* __restrict__ Wd, const float* __restrict__ bd,
    const float* __restrict__ W1, const float* __restrict__ W2,
    unsigned short* __restrict__ X, float* __restrict__ base,
    unsigned short* __restrict__ W1s, unsigned short* __restrict__ W2s,
    float* __restrict__ st)
{
    int tid = threadIdx.x;
    if (blockIdx.x >= 1024) {
        int c = (blockIdx.x - 1024) * 256 + tid;     // 0..48383
        if (c < 256) {
            for (int i = tid; i < 6656; i += 256) st[i] = 0.f;  // 4 replicas
        }
        const float* W; unsigned short* dst; int K; int cc;
        if (c < 25088) { W = W1; dst = W1s; K = 429; cc = c; }
        else           { W = W2; dst = W2s; K = 400; cc = c - 25088; }
        int n  = cc % 448;
        int q  = (cc / 448) & 3;
        int kt = cc / 1792;
        unsigned short o[8];
        #pragma unroll
        for (int j = 0; j < 8; ++j) {
            int k = kt * 32 + q * 8 + j;
            float v = (n < NH && k < K) ? W[(size_t)k * NH + n] : 0.f;
            o[j] = f2bf(v);
        }
        *(uint4v*)(dst + (size_t)cc * 8) = *(uint4v*)o;
        return;
    }
    int r = blockIdx.x * 16 + (tid >> 4);
    int k = tid & 15;
    const int* idxp = Xcat + (size_t)r * NF;
    unsigned short* xrow = X + (size_t)r * XPAD;

    float s = 0.f, ss = 0.f;
    #pragma unroll
    for (int f = 0; f < NF; ++f) {
        int idx = idxp[f];
        float v = emb[((size_t)f * NV + idx) * 16 + k];
        s += v; ss += v * v;
        xrow[f * 16 + k] = f2bf(v);
    }
    float fmsum = fm1[(size_t)k * NV + idxp[k]];
    if (k < NF - 16) fmsum += fm1[(size_t)(k + 16) * NV + idxp[k + 16]];
    float dsum = 0.f;
    if (k < ND) {
        float xd = Xdense[(size_t)r * ND + k];
        dsum = xd * Wd[k];
        xrow[NF * 16 + k] = f2bf(xd);
    }
    xrow[429 + k] = 0;
    if (k < 3) xrow[445 + k] = 0;

    float ix = s * s - ss;
    float rf = fmsum, rd = dsum;
    #pragma unroll
    for (int off = 8; off; off >>= 1) {
        ix += __shfl_xor(ix, off, 16);
        rf += __shfl_xor(rf, off, 16);
        rd += __shfl_xor(rd, off, 16);
    }
    if (k == 0) base[r] = 0.5f * ix + rf + rd + bd[0];
}

// =====================================================================
// gemm_v5 (champion): barrier-free per-wave GEMM + T4 counted-vmcnt
// double-buffered slices. grid 256 x 512. Wave wv=(rg<<2)|w4:
// rows bid*64+rg*32 (2x16), col quarter w4 (NFW=7,6,6,6).
// Per-tile VMEM group = NFW+2 -> steady-state wait vmcnt(9|8).
// =====================================================================
template<int NT, int LDA, bool APPLY_BN>
__global__ __launch_bounds__(512, 2) void gemm_v5(
    const unsigned short* __restrict__ A,
    const unsigned short* __restrict__ Wst,
    const float* __restrict__ bias,
    const float* __restrict__ st_all,
    const float* __restrict__ g, const float* __restrict__ be,
    unsigned short* __restrict__ Z, int ldz, int padZ,
    float* __restrict__ st_out, int sumOff, int sqOff)
{
    __shared__ __align__(16) unsigned short slices[51200];  // 2 bufs x 25600
    __shared__ float alpha_s[416], beta_s[416];

    const int tid = threadIdx.x, bid = blockIdx.x;
    const int lane = tid & 63, wv = tid >> 6;
    const int rg = wv >> 2, w4 = wv & 3;
    const int l15 = lane & 15, qh = lane >> 4;
    const int cb = (w4 == 0) ? 0 : (112 + (w4 - 1) * 96);
    const int NFW = (w4 == 0) ? 7 : 6;
    const int soff = rg * 12800 + ((w4 == 0) ? 0 : (3584 + (w4 - 1) * 3072));
    const int arowA = bid * 64 + rg * 32 + l15;
    const int arowB = arowA + 16;

    if constexpr (APPLY_BN) {
        if (tid < 416) {
            int c = tid;
            float a = 0.f, b = 0.f;
            if (c < NH) {
                float gs = 0.f, gq = 0.f;
                #pragma unroll
                for (int cp = 0; cp < 4; ++cp) {
                    gs += st_all[cp * 1664 + c];
                    gq += st_all[cp * 1664 + 416 + c];
                }
                float mean = gs * (1.f / 16384.f);
                float var  = gq * (1.f / 16384.f) - mean * mean;
                a = g[c] * rsqrtf(var + EPS);
                b = be[c] - mean * a;
            }
            alpha_s[c] = a; beta_s[c] = b;
        }
        __syncthreads();
    }

    f32x4 acc0[7], acc1[7];
    #pragma unroll
    for (int i = 0; i < 7; ++i) { acc0[i] = f32x4{0,0,0,0}; acc1[i] = f32x4{0,0,0,0}; }

    auto stageW = [&](int kt, int buf) {
        unsigned short* sl = slices + buf * 25600 + soff;
        #pragma unroll
        for (int i = 0; i < 7; ++i) if (i < NFW) {
            int ci = (kt * 4 + qh) * 448 + cb + i * 16 + l15;
            gload_lds16(Wst + (size_t)ci * 8, sl + i * 512);
        }
    };
    auto ldA = [&](int kt, short8& a, short8& b) {
        a = *(const short8*)(A + (size_t)arowA * LDA + kt * 32 + qh * 8);
        b = *(const short8*)(A + (size_t)arowB * LDA + kt * 32 + qh * 8);
    };
    auto waitN = [&]() {
        if (w4 == 0) asm volatile("s_waitcnt vmcnt(9)" ::: "memory");
        else         asm volatile("s_waitcnt vmcnt(8)" ::: "memory");
        __builtin_amdgcn_sched_barrier(0);
    };
    auto wait0 = [&]() {
        asm volatile("s_waitcnt vmcnt(0)" ::: "memory");
        __builtin_amdgcn_sched_barrier(0);
    };
    auto waitlg = [&]() {
        asm volatile("s_waitcnt lgkmcnt(0)" ::: "memory");
        __builtin_amdgcn_sched_barrier(0);
    };

    auto phase = [&](int kt, int buf, bool last, bool issue,
                     short8& afA, short8& afB) {
        if (last) wait0(); else waitN();
        const unsigned short* sl = slices + buf * 25600 + soff;
        short8 bf[7];
        #pragma unroll
        for (int i = 0; i < 7; ++i) if (i < NFW)
            bf[i] = *(const short8*)(sl + i * 512 + lane * 8);
        short8 aA = afA, aB = afB;
        waitlg();
        if (issue) { stageW(kt + 2, buf); ldA(kt + 2, afA, afB); }
        if constexpr (APPLY_BN) {
            const int k0 = kt * 32 + qh * 8;
            #pragma unroll
            for (int j = 0; j < 8; ++j) {
                float al = alpha_s[k0 + j], bt = beta_s[k0 + j];
                aA[j] = (short)f2bf(fmaxf(0.f, al * bf2f((unsigned short)aA[j]) + bt));
                aB[j] = (short)f2bf(fmaxf(0.f, al * bf2f((unsigned short)aB[j]) + bt));
            }
        }
        #pragma unroll
        for (int i = 0; i < 7; ++i) if (i < NFW) {
            acc0[i] = __builtin_amdgcn_mfma_f32_16x16x32_bf16(aA, bf[i], acc0[i], 0, 0, 0);
            acc1[i] = __builtin_amdgcn_mfma_f32_16x16x32_bf16(aB, bf[i], acc1[i], 0, 0, 0);
        }
    };

    short8 afA0, afB0, afA1, afB1;
    stageW(0, 0); ldA(0, afA0, afB0);
    stageW(1, 1); ldA(1, afA1, afB1);

    int kt2 = 0;
    for (; kt2 + 3 < NT; kt2 += 2) {
        phase(kt2,     0, false, true, afA0, afB0);
        phase(kt2 + 1, 1, false, true, afA1, afB1);
    }
    if constexpr (NT % 2 == 0) {
        phase(NT - 2, 0, false, false, afA0, afB0);
        phase(NT - 1, 1, true,  false, afA1, afB1);
    } else {
        phase(NT - 3, 0, false, true,  afA0, afB0);
        phase(NT - 2, 1, false, false, afA1, afB1);
        phase(NT - 1, 0, true,  false, afA0, afB0);
    }

    float* stc = st_out + (bid & 3) * 1664;
    #pragma unroll
    for (int i = 0; i < 7; ++i) if (i < NFW) {
        int col = cb + i * 16 + l15;
        float bv = bias[col];
        float ps = 0.f, pq = 0.f;
        #pragma unroll
        for (int q = 0; q < 4; ++q) {
            float v0 = acc0[i][q] + bv;
            float v1 = acc1[i][q] + bv;
            Z[(size_t)(bid * 64 + rg * 32 + qh * 4 + q) * ldz + col] = f2bf(v0);
            Z[(size_t)(bid * 64 + rg * 32 + 16 + qh * 4 + q) * ldz + col] = f2bf(v1);
            ps += v0 + v1; pq += v0 * v0 + v1 * v1;
        }
        ps += __shfl_xor(ps, 16, 64); ps += __shfl_xor(ps, 32, 64);
        pq += __shfl_xor(pq, 16, 64); pq += __shfl_xor(pq, 32, 64);
        if (qh == 0) {
            atomicAdd(&stc[sumOff + col], ps);
            atomicAdd(&stc[sqOff + col], pq);
        }
    }
    if (padZ && w4 == 3) {
        #pragma unroll
        for (int rr = 0; rr < 8; ++rr)
            Z[(size_t)(bid * 64 + rg * 32 + rr * 4 + qh) * ldz + 400 + l15] = 0;
    }
}

// =====================================================================
// final: BN2 from replicas, then out[r] = base[r] + relu(.)·W3 + b3
// =====================================================================
__global__ __launch_bounds__(256) void final_kernel(
    const unsigned short* __restrict__ Z2,
    const float* __restrict__ st_all,
    const float* __restrict__ g2, const float* __restrict__ be2,
    const float* __restrict__ W3, const float* __restrict__ b3,
    const float* __restrict__ base, float* __restrict__ out)
{
    __shared__ float a2s[NH], b2s[NH], w3s[NH];
    int tid = threadIdx.x;
    for (int c = tid; c < NH; c += 256) {
        float gs = 0.f, gq = 0.f;
        #pragma unroll
        for (int cp = 0; cp < 4; ++cp) {
            gs += st_all[cp * 1664 + 832 + c];
            gq += st_all[cp * 1664 + 1248 + c];
        }
        float mean = gs * (1.f / 16384.f);
        float var  = gq * (1.f / 16384.f) - mean * mean;
        float a = g2[c] * rsqrtf(var + EPS);
        a2s[c] = a;
        b2s[c] = be2[c] - mean * a;
        w3s[c] = W3[c];
    }
    __syncthreads();
    int lane = tid & 63;
    int wv = tid >> 6;
    bool act = lane < 50;
    int cb = lane * 8;
    float al[8], bb[8], w3[8];
    #pragma unroll
    for (int j = 0; j < 8; ++j) {
        al[j] = act ? a2s[cb + j] : 0.f;
        bb[j] = act ? b2s[cb + j] : 0.f;
        w3[j] = act ? w3s[cb + j] : 0.f;
    }
    int r0 = blockIdx.x * 32 + wv * 8;
    float bias3 = b3[0];
    for (int t = 0; t < 8; t += 2) {
        int r = r0 + t;
        float acc0 = 0.f, acc1 = 0.f;
        if (act) {
            short8 z0 = *(const short8*)(Z2 + (size_t)r * ZPAD + cb);
            short8 z1 = *(const short8*)(Z2 + (size_t)(r + 1) * ZPAD + cb);
            #pragma unroll
            for (int j = 0; j < 8; ++j) {
                acc0 += fmaxf(0.f, al[j] * bf2f((unsigned short)z0[j]) + bb[j]) * w3[j];
                acc1 += fmaxf(0.f, al[j] * bf2f((unsigned short)z1[j]) + bb[j]) * w3[j];
            }
        }
        #pragma unroll
        for (int off = 32; off; off >>= 1) {
            acc0 += __shfl_xor(acc0, off, 64);
            acc1 += __shfl_xor(acc1, off, 64);
        }
        if (lane == 0) out[r] = base[r] + acc0 + bias3;
        if (lane == 1) out[r + 1] = base[r + 1] + acc1 + bias3;
    }
}

// =====================================================================
extern "C" void kernel_launch(void* const* d_in, const int* in_sizes, int n_in,
                              void* d_out, int out_size, void* d_ws, size_t ws_size,
                              hipStream_t stream)
{
    const int*   Xcat = (const int*)d_in[0];
    const float* Xd   = (const float*)d_in[1];
    const float* fm1  = (const float*)d_in[2];
    const float* emb  = (const float*)d_in[3];
    const float* Wd   = (const float*)d_in[4];
    const float* bd   = (const float*)d_in[5];
    const float* W1   = (const float*)d_in[6];
    const float* b1   = (const float*)d_in[7];
    const float* g1   = (const float*)d_in[8];
    const float* be1  = (const float*)d_in[9];
    const float* W2   = (const float*)d_in[10];
    const float* b2   = (const float*)d_in[11];
    const float* g2   = (const float*)d_in[12];
    const float* be2  = (const float*)d_in[13];
    const float* W3   = (const float*)d_in[14];
    const float* b3   = (const float*)d_in[15];

    char* ws = (char*)d_ws;
    unsigned short* X   = (unsigned short*)(ws + X_OFF);
    unsigned short* Z1  = (unsigned short*)(ws + Z1_OFF);
    unsigned short* Z2  = X;   // X dead after GEMM1
    unsigned short* W1s = (unsigned short*)(ws + W1S_OFF);
    unsigned short* W2s = (unsigned short*)(ws + W2S_OFF);
    float* base = (float*)(ws + BASE_OFF);
    float* st   = (float*)(ws + ST_OFF);
    float* out  = (float*)d_out;

    // 1: gather + W staging + 4-replica stat zero
    gather_prep<<<1213, 256, 0, stream>>>(Xcat, Xd, fm1, emb, Wd, bd, W1, W2,
                                          X, base, W1s, W2s, st);

    // 2: Z1 = X @ W1 + b1, stats1
    gemm_v5<14, XPAD, false><<<256, 512, 0, stream>>>(
        X, W1s, b1, nullptr, nullptr, nullptr, Z1, ZPAD, 1, st, 0, 416);

    // 3: Z2 = relu(bn1(Z1)) @ W2 + b2, stats2
    gemm_v5<13, ZPAD, true><<<256, 512, 0, stream>>>(
        Z1, W2s, b2, st, g1, be1, Z2, ZPAD, 0, st, 832, 1248);

    // 4: out = base + relu(bn2(Z2))·W3 + b3
    final_kernel<<<512, 256, 0, stream>>>(Z2, st, g2, be2, W3, b3, base, out);
}